// Round 3
// baseline (146.874 us; speedup 1.0000x reference)
//
#include <hip/hip_runtime.h>
#include <hip/hip_bf16.h>
#include <stdint.h>

// SimCLR loss, n=8192, d=128, T=0.07.
//  k_normalize: fp32 features -> row-L2-normalized bf16 fn (ws); zeroes out[0]
//  k_simexp:    E_part[row][slice] = sum_{j in slice} exp2((dot_ij - 1)*s)
//               MFMA bf16, A-fragments pinned in VGPRs (asm pin, no remat),
//               B direct per-lane global loads (L1/L2-resident, no LDS/barriers).
//               Diagonal included; removed analytically in finalize.
//  k_finalize:  per row term = 1/T + ln(E - exp2((selfdot-1)*s)) - posdot/T;
//               block partial -> atomicAdd(out, partial/N).

#define N_ROWS 8192
#define DIM    128
#define HALF_N 4096
#define N_SLICES 32
#define JCOLS (N_ROWS / N_SLICES)      // 256 cols per slice
#define NT (JCOLS / 16)                // 16 j-tiles per wave
#define ROWS_PER_BLOCK 256             // 4 waves * 64 rows

static constexpr float INV_T = 14.285714285714286f;   // 1/0.07
static constexpr float SCALE = 20.60992915555662f;    // log2(e)/0.07

typedef __attribute__((ext_vector_type(8))) short short8;   // 8 bf16
typedef __attribute__((ext_vector_type(4))) float f32x4;

#if __has_builtin(__builtin_amdgcn_exp2f)
__device__ inline float fast_exp2(float x) { return __builtin_amdgcn_exp2f(x); }
#else
__device__ inline float fast_exp2(float x) { return exp2f(x); }
#endif

__device__ inline float bf_lo(uint32_t u) { return __uint_as_float(u << 16); }
__device__ inline float bf_hi(uint32_t u) { return __uint_as_float(u & 0xFFFF0000u); }
__device__ inline uint16_t f2bf(float x) {
    uint32_t u = __float_as_uint(x);
    return (uint16_t)((u + 0x7FFFu + ((u >> 16) & 1u)) >> 16);   // RNE
}

// ---------------- kernel 1: row L2-normalize, fp32 -> bf16 ----------------
__global__ __launch_bounds__(256) void k_normalize(const float* __restrict__ f,
                                                   uint16_t* __restrict__ fn,
                                                   float* __restrict__ out) {
    if (blockIdx.x == 0 && threadIdx.x == 0) out[0] = 0.0f;   // init for atomics
    int wid  = (blockIdx.x * blockDim.x + threadIdx.x) >> 6;   // one wave per row
    int lane = threadIdx.x & 63;
    const float2* src = (const float2*)(f + (size_t)wid * DIM);
    float2 v = src[lane];
    float ss = v.x * v.x + v.y * v.y;
    #pragma unroll
    for (int m = 1; m < 64; m <<= 1) ss += __shfl_xor(ss, m, 64);
    float inv = rsqrtf(ss);
    ushort2 o;
    o.x = f2bf(v.x * inv);
    o.y = f2bf(v.y * inv);
    ((ushort2*)(fn + (size_t)wid * DIM))[lane] = o;
}

// ---------------- kernel 2: fused sim + exp-sum (MFMA) ----------------
// Grid (N_ROWS/256, N_SLICES); block = 4 waves, each wave owns 64 rows x slice.
// No LDS, no barriers: B tiles stream through L1/L2 (fn = 2 MiB, L2-resident).
__global__ __launch_bounds__(256, 3) void k_simexp(const uint16_t* __restrict__ fn,
                                                   float* __restrict__ E_part) {
    const int lane  = threadIdx.x & 63;
    const int w     = threadIdx.x >> 6;
    const int ib    = blockIdx.x * ROWS_PER_BLOCK + w * 64;
    const int slice = blockIdx.y;
    const int lr = lane & 15;
    const int lk = lane >> 4;

    const short8* fn8 = (const short8*)fn;

    // A fragments: row ib+mt*16+lr, dims kc*32+lk*8..+8. Loaded ONCE, pinned
    // in VGPRs via opaque asm (prevents rematerialization inside jt loop).
    short8 Af[4][4];
    #pragma unroll
    for (int mt = 0; mt < 4; ++mt)
        #pragma unroll
        for (int kc = 0; kc < 4; ++kc) {
            Af[mt][kc] = fn8[(size_t)(ib + mt * 16 + lr) * 16 + kc * 4 + lk];
            asm volatile("" : "+v"(Af[mt][kc]));
        }

    float es[4][4];
    #pragma unroll
    for (int mt = 0; mt < 4; ++mt)
        #pragma unroll
        for (int r = 0; r < 4; ++r) es[mt][r] = 0.0f;

    const short8* bbase = fn8 + (size_t)slice * JCOLS * 16 + lr * 16 + lk;

    for (int jt = 0; jt < NT; ++jt) {
        const short8* bp = bbase + (size_t)jt * 16 * 16;
        short8 Bf[4];
        #pragma unroll
        for (int kc = 0; kc < 4; ++kc)
            Bf[kc] = bp[kc * 4];
        #pragma unroll
        for (int mt = 0; mt < 4; ++mt) {
            f32x4 acc = {0.0f, 0.0f, 0.0f, 0.0f};
            #pragma unroll
            for (int kc = 0; kc < 4; ++kc)
                acc = __builtin_amdgcn_mfma_f32_16x16x32_bf16(Af[mt][kc], Bf[kc], acc, 0, 0, 0);
            #pragma unroll
            for (int r = 0; r < 4; ++r)
                es[mt][r] += fast_exp2(fmaf(acc[r], SCALE, -SCALE));
        }
    }

    // C/D layout: col = lane&15, row = lk*4 + r. Sum over the 16 col-lanes.
    #pragma unroll
    for (int mt = 0; mt < 4; ++mt)
        #pragma unroll
        for (int r = 0; r < 4; ++r) {
            float v = es[mt][r];
            v += __shfl_xor(v, 1, 64);
            v += __shfl_xor(v, 2, 64);
            v += __shfl_xor(v, 4, 64);
            v += __shfl_xor(v, 8, 64);
            if (lr == 0)
                E_part[(size_t)(ib + mt * 16 + lk * 4 + r) * N_SLICES + slice] = v;
        }
}

// ---------------- kernel 3: finalize + mean (atomic) ----------------
__global__ __launch_bounds__(256) void k_finalize(const uint16_t* __restrict__ fn,
                                                  const float* __restrict__ E_part,
                                                  float* __restrict__ out) {
    __shared__ float sm[4];
    int wid  = (blockIdx.x * blockDim.x + threadIdx.x) >> 6;   // one wave per row
    int lane = threadIdx.x & 63;
    int partner = (wid + HALF_N) & (N_ROWS - 1);
    const uint32_t* fr = (const uint32_t*)(fn + (size_t)wid * DIM);
    const uint32_t* pr = (const uint32_t*)(fn + (size_t)partner * DIM);
    uint32_t a = fr[lane], p = pr[lane];
    float a0 = bf_lo(a), a1 = bf_hi(a);
    float p0 = bf_lo(p), p1 = bf_hi(p);
    float sd = a0 * a0 + a1 * a1;       // self dot  (diagonal recompute)
    float pd = a0 * p0 + a1 * p1;       // positive-pair dot
    #pragma unroll
    for (int m = 1; m < 64; m <<= 1) {
        sd += __shfl_xor(sd, m, 64);
        pd += __shfl_xor(pd, m, 64);
    }
    float e = (lane < N_SLICES) ? E_part[(size_t)wid * N_SLICES + lane] : 0.0f;
    #pragma unroll
    for (int m = 1; m < 64; m <<= 1) e += __shfl_xor(e, m, 64);
    if (lane == 0) {
        float ep = e - fast_exp2(fmaf(sd, SCALE, -SCALE));   // remove diagonal
        sm[threadIdx.x >> 6] = INV_T + logf(ep) - pd * INV_T;
    }
    __syncthreads();
    if (threadIdx.x == 0)
        atomicAdd(out, (sm[0] + sm[1] + sm[2] + sm[3]) * (1.0f / N_ROWS));
}

extern "C" void kernel_launch(void* const* d_in, const int* in_sizes, int n_in,
                              void* d_out, int out_size, void* d_ws, size_t ws_size,
                              hipStream_t stream) {
    const float* feat = (const float*)d_in[0];
    float* out = (float*)d_out;

    // ws: fn (bf16, 2 MiB) | E_part (f32, 8192*32*4 = 1 MiB)
    uint16_t* fn  = (uint16_t*)d_ws;
    float* E_part = (float*)((char*)d_ws + (size_t)N_ROWS * DIM * 2);

    k_normalize<<<dim3(N_ROWS / 4), dim3(256), 0, stream>>>(feat, fn, out);
    k_simexp<<<dim3(N_ROWS / ROWS_PER_BLOCK, N_SLICES), dim3(256), 0, stream>>>(fn, E_part);
    k_finalize<<<dim3(N_ROWS / 4), dim3(256), 0, stream>>>(fn, E_part, out);
}

// Round 4
// 81.431 us; speedup vs baseline: 1.8037x; 1.8037x over previous
//
#include <hip/hip_runtime.h>
#include <hip/hip_bf16.h>
#include <stdint.h>

// SimCLR loss, n=8192, d=128, T=0.07.
//  k_normalize: fp32 features -> row-L2-normalized bf16 fn (ws)
//  k_simexp:    E_part[row][slice] = sum_{j in slice} exp2((dot_ij - 1)*s)
//               MFMA bf16. A-fragments in VGPRs; amdgpu_waves_per_eu(4,4)
//               sets a 128-VGPR budget so the allocator neither remats the
//               A-set from L2 every iter (R1 failure, 64-reg target) nor
//               spills (R3 failure, asm pins). B: direct per-lane global
//               loads, L1/L2-resident, no LDS, no barriers.
//  k_finalize:  per row term = 1/T + ln(E - exp2((selfdot-1)*s)) - posdot/T;
//               block partial -> atomicAdd(out, partial/N). out pre-memset.

#define N_ROWS 8192
#define DIM    128
#define HALF_N 4096
#define N_SLICES 32
#define JCOLS (N_ROWS / N_SLICES)      // 256 cols per slice
#define NT (JCOLS / 16)                // 16 j-tiles per wave
#define ROWS_PER_BLOCK 256             // 4 waves * 64 rows

static constexpr float INV_T = 14.285714285714286f;   // 1/0.07
static constexpr float SCALE = 20.60992915555662f;    // log2(e)/0.07

typedef __attribute__((ext_vector_type(8))) short short8;   // 8 bf16
typedef __attribute__((ext_vector_type(4))) float f32x4;

#if __has_builtin(__builtin_amdgcn_exp2f)
__device__ inline float fast_exp2(float x) { return __builtin_amdgcn_exp2f(x); }
#else
__device__ inline float fast_exp2(float x) { return exp2f(x); }
#endif

__device__ inline float bf_lo(uint32_t u) { return __uint_as_float(u << 16); }
__device__ inline float bf_hi(uint32_t u) { return __uint_as_float(u & 0xFFFF0000u); }
__device__ inline uint16_t f2bf(float x) {
    uint32_t u = __float_as_uint(x);
    return (uint16_t)((u + 0x7FFFu + ((u >> 16) & 1u)) >> 16);   // RNE
}

// ---------------- kernel 1: row L2-normalize, fp32 -> bf16 ----------------
__global__ __launch_bounds__(256) void k_normalize(const float* __restrict__ f,
                                                   uint16_t* __restrict__ fn) {
    int wid  = (blockIdx.x * blockDim.x + threadIdx.x) >> 6;   // one wave per row
    int lane = threadIdx.x & 63;
    const float2* src = (const float2*)(f + (size_t)wid * DIM);
    float2 v = src[lane];
    float ss = v.x * v.x + v.y * v.y;
    #pragma unroll
    for (int m = 1; m < 64; m <<= 1) ss += __shfl_xor(ss, m, 64);
    float inv = rsqrtf(ss);
    ushort2 o;
    o.x = f2bf(v.x * inv);
    o.y = f2bf(v.y * inv);
    ((ushort2*)(fn + (size_t)wid * DIM))[lane] = o;
}

// ---------------- kernel 2: fused sim + exp-sum (MFMA) ----------------
// Grid (N_ROWS/256, N_SLICES); block = 4 waves, each wave owns 64 rows x slice.
__global__ __launch_bounds__(256)
__attribute__((amdgpu_waves_per_eu(4, 4)))
void k_simexp(const uint16_t* __restrict__ fn, float* __restrict__ E_part) {
    const int lane  = threadIdx.x & 63;
    const int w     = threadIdx.x >> 6;
    const int ib    = blockIdx.x * ROWS_PER_BLOCK + w * 64;
    const int slice = blockIdx.y;
    const int lr = lane & 15;
    const int lk = lane >> 4;

    const short8* fn8 = (const short8*)fn;

    // A fragments: row ib+mt*16+lr, dims kc*32+lk*8..+8. Loaded once; the
    // 128-VGPR budget from waves_per_eu(4,4) lets them stay resident.
    short8 Af[4][4];
    #pragma unroll
    for (int mt = 0; mt < 4; ++mt)
        #pragma unroll
        for (int kc = 0; kc < 4; ++kc)
            Af[mt][kc] = fn8[(size_t)(ib + mt * 16 + lr) * 16 + kc * 4 + lk];

    float es[4][4];
    #pragma unroll
    for (int mt = 0; mt < 4; ++mt)
        #pragma unroll
        for (int r = 0; r < 4; ++r) es[mt][r] = 0.0f;

    const short8* bbase = fn8 + (size_t)slice * JCOLS * 16 + lr * 16 + lk;

    for (int jt = 0; jt < NT; ++jt) {
        const short8* bp = bbase + (size_t)jt * 16 * 16;
        short8 Bf[4];
        #pragma unroll
        for (int kc = 0; kc < 4; ++kc)
            Bf[kc] = bp[kc * 4];
        #pragma unroll
        for (int mt = 0; mt < 4; ++mt) {
            f32x4 acc = {0.0f, 0.0f, 0.0f, 0.0f};
            #pragma unroll
            for (int kc = 0; kc < 4; ++kc)
                acc = __builtin_amdgcn_mfma_f32_16x16x32_bf16(Af[mt][kc], Bf[kc], acc, 0, 0, 0);
            #pragma unroll
            for (int r = 0; r < 4; ++r)
                es[mt][r] += fast_exp2(fmaf(acc[r], SCALE, -SCALE));
        }
    }

    // C/D layout: col = lane&15, row = lk*4 + r. Sum over the 16 col-lanes.
    #pragma unroll
    for (int mt = 0; mt < 4; ++mt)
        #pragma unroll
        for (int r = 0; r < 4; ++r) {
            float v = es[mt][r];
            v += __shfl_xor(v, 1, 64);
            v += __shfl_xor(v, 2, 64);
            v += __shfl_xor(v, 4, 64);
            v += __shfl_xor(v, 8, 64);
            if (lr == 0)
                E_part[(size_t)(ib + mt * 16 + lk * 4 + r) * N_SLICES + slice] = v;
        }
}

// ---------------- kernel 3: finalize + mean (atomic) ----------------
__global__ __launch_bounds__(256) void k_finalize(const uint16_t* __restrict__ fn,
                                                  const float* __restrict__ E_part,
                                                  float* __restrict__ out) {
    __shared__ float sm[4];
    int wid  = (blockIdx.x * blockDim.x + threadIdx.x) >> 6;   // one wave per row
    int lane = threadIdx.x & 63;
    int partner = (wid + HALF_N) & (N_ROWS - 1);
    const uint32_t* fr = (const uint32_t*)(fn + (size_t)wid * DIM);
    const uint32_t* pr = (const uint32_t*)(fn + (size_t)partner * DIM);
    uint32_t a = fr[lane], p = pr[lane];
    float a0 = bf_lo(a), a1 = bf_hi(a);
    float p0 = bf_lo(p), p1 = bf_hi(p);
    float sd = a0 * a0 + a1 * a1;       // self dot  (diagonal recompute)
    float pd = a0 * p0 + a1 * p1;       // positive-pair dot
    #pragma unroll
    for (int m = 1; m < 64; m <<= 1) {
        sd += __shfl_xor(sd, m, 64);
        pd += __shfl_xor(pd, m, 64);
    }
    float e = (lane < N_SLICES) ? E_part[(size_t)wid * N_SLICES + lane] : 0.0f;
    #pragma unroll
    for (int m = 1; m < 64; m <<= 1) e += __shfl_xor(e, m, 64);
    if (lane == 0) {
        float ep = e - fast_exp2(fmaf(sd, SCALE, -SCALE));   // remove diagonal
        sm[threadIdx.x >> 6] = INV_T + logf(ep) - pd * INV_T;
    }
    __syncthreads();
    if (threadIdx.x == 0)
        atomicAdd(out, (sm[0] + sm[1] + sm[2] + sm[3]) * (1.0f / N_ROWS));
}

extern "C" void kernel_launch(void* const* d_in, const int* in_sizes, int n_in,
                              void* d_out, int out_size, void* d_ws, size_t ws_size,
                              hipStream_t stream) {
    const float* feat = (const float*)d_in[0];
    float* out = (float*)d_out;

    // ws: fn (bf16, 2 MiB) | E_part (f32, 8192*32*4 = 1 MiB)
    uint16_t* fn  = (uint16_t*)d_ws;
    float* E_part = (float*)((char*)d_ws + (size_t)N_ROWS * DIM * 2);

    hipMemsetAsync(out, 0, sizeof(float), stream);
    k_normalize<<<dim3(N_ROWS / 4), dim3(256), 0, stream>>>(feat, fn);
    k_simexp<<<dim3(N_ROWS / ROWS_PER_BLOCK, N_SLICES), dim3(256), 0, stream>>>(fn, E_part);
    k_finalize<<<dim3(N_ROWS / 4), dim3(256), 0, stream>>>(fn, E_part, out);
}

// Round 5
// 77.479 us; speedup vs baseline: 1.8957x; 1.0510x over previous
//
#include <hip/hip_runtime.h>
#include <hip/hip_bf16.h>
#include <stdint.h>

// SimCLR loss, n=8192, d=128, T=0.07.
//  k_normalize: fp32 features -> row-L2-normalized bf16 fn (ws); zeroes out[0]
//  k_simexp:    E_part[row][slice] = sum_{j in slice} exp2((dot_ij - 1)*s)
//               MFMA bf16. A-fragments loaded ONCE via inline-asm
//               global_load_dwordx4 (compiler cannot rematerialize asm
//               outputs -> they stay VGPR-resident across the j-loop; this
//               was the R1/R4 43us bottleneck: ~1 GB/iter-loop of A reloads
//               through L1/L2). waves_per_eu(3) gives a ~170-reg budget so
//               the 64 pinned regs don't force scratch spills (R3 failure).
//               B: direct per-lane global loads, L1/L2-resident, no LDS.
//  k_finalize:  per row term = 1/T + ln(E - exp2((selfdot-1)*s)) - posdot/T;
//               block partial -> atomicAdd(out, partial/N).

#define N_ROWS 8192
#define DIM    128
#define HALF_N 4096
#define N_SLICES 32
#define JCOLS (N_ROWS / N_SLICES)      // 256 cols per slice
#define NT (JCOLS / 16)                // 16 j-tiles per wave
#define ROWS_PER_BLOCK 256             // 4 waves * 64 rows

static constexpr float INV_T = 14.285714285714286f;   // 1/0.07
static constexpr float SCALE = 20.60992915555662f;    // log2(e)/0.07

typedef __attribute__((ext_vector_type(8))) short short8;   // 8 bf16 = 4 VGPR
typedef __attribute__((ext_vector_type(4))) float f32x4;

#if __has_builtin(__builtin_amdgcn_exp2f)
__device__ inline float fast_exp2(float x) { return __builtin_amdgcn_exp2f(x); }
#else
__device__ inline float fast_exp2(float x) { return exp2f(x); }
#endif

__device__ inline float bf_lo(uint32_t u) { return __uint_as_float(u << 16); }
__device__ inline float bf_hi(uint32_t u) { return __uint_as_float(u & 0xFFFF0000u); }
__device__ inline uint16_t f2bf(float x) {
    uint32_t u = __float_as_uint(x);
    return (uint16_t)((u + 0x7FFFu + ((u >> 16) & 1u)) >> 16);   // RNE
}

// ---------------- kernel 1: row L2-normalize, fp32 -> bf16 ----------------
__global__ __launch_bounds__(256) void k_normalize(const float* __restrict__ f,
                                                   uint16_t* __restrict__ fn,
                                                   float* __restrict__ out) {
    if (blockIdx.x == 0 && threadIdx.x == 0) out[0] = 0.0f;   // init for atomics
    int wid  = (blockIdx.x * blockDim.x + threadIdx.x) >> 6;   // one wave per row
    int lane = threadIdx.x & 63;
    const float2* src = (const float2*)(f + (size_t)wid * DIM);
    float2 v = src[lane];
    float ss = v.x * v.x + v.y * v.y;
    #pragma unroll
    for (int m = 1; m < 64; m <<= 1) ss += __shfl_xor(ss, m, 64);
    float inv = rsqrtf(ss);
    ushort2 o;
    o.x = f2bf(v.x * inv);
    o.y = f2bf(v.y * inv);
    ((ushort2*)(fn + (size_t)wid * DIM))[lane] = o;
}

// ---------------- kernel 2: fused sim + exp-sum (MFMA) ----------------
// Grid (N_ROWS/256, N_SLICES); block = 4 waves, each wave owns 64 rows x slice.
__global__ __launch_bounds__(256)
__attribute__((amdgpu_waves_per_eu(3)))
void k_simexp(const uint16_t* __restrict__ fn, float* __restrict__ E_part) {
    const int lane  = threadIdx.x & 63;
    const int w     = threadIdx.x >> 6;
    const int ib    = blockIdx.x * ROWS_PER_BLOCK + w * 64;
    const int slice = blockIdx.y;
    const int lr = lane & 15;
    const int lk = lane >> 4;

    const short8* fn8 = (const short8*)fn;

    // A fragments: row ib+mt*16+lr, dims kc*32+lk*8..+8. Loaded ONCE via
    // inline asm -> outputs are opaque to the compiler: no remat, no sink.
    short8 Af[4][4];
    #pragma unroll
    for (int mt = 0; mt < 4; ++mt)
        #pragma unroll
        for (int kc = 0; kc < 4; ++kc) {
            const short8* ap = fn8 + (size_t)(ib + mt * 16 + lr) * 16 + kc * 4 + lk;
            asm volatile("global_load_dwordx4 %0, %1, off"
                         : "=v"(Af[mt][kc]) : "v"(ap));
        }
    asm volatile("s_waitcnt vmcnt(0)" ::: "memory");

    float es[4][4];
    #pragma unroll
    for (int mt = 0; mt < 4; ++mt)
        #pragma unroll
        for (int r = 0; r < 4; ++r) es[mt][r] = 0.0f;

    const short8* bbase = fn8 + (size_t)slice * JCOLS * 16 + lr * 16 + lk;

    for (int jt = 0; jt < NT; ++jt) {
        const short8* bp = bbase + (size_t)jt * 16 * 16;
        short8 Bf[4];
        #pragma unroll
        for (int kc = 0; kc < 4; ++kc)
            Bf[kc] = bp[kc * 4];
        #pragma unroll
        for (int mt = 0; mt < 4; ++mt) {
            f32x4 acc = {0.0f, 0.0f, 0.0f, 0.0f};
            #pragma unroll
            for (int kc = 0; kc < 4; ++kc)
                acc = __builtin_amdgcn_mfma_f32_16x16x32_bf16(Af[mt][kc], Bf[kc], acc, 0, 0, 0);
            #pragma unroll
            for (int r = 0; r < 4; ++r)
                es[mt][r] += fast_exp2(fmaf(acc[r], SCALE, -SCALE));
        }
    }

    // C/D layout: col = lane&15, row = lk*4 + r. Sum over the 16 col-lanes.
    #pragma unroll
    for (int mt = 0; mt < 4; ++mt)
        #pragma unroll
        for (int r = 0; r < 4; ++r) {
            float v = es[mt][r];
            v += __shfl_xor(v, 1, 64);
            v += __shfl_xor(v, 2, 64);
            v += __shfl_xor(v, 4, 64);
            v += __shfl_xor(v, 8, 64);
            if (lr == 0)
                E_part[(size_t)(ib + mt * 16 + lk * 4 + r) * N_SLICES + slice] = v;
        }
}

// ---------------- kernel 3: finalize + mean (atomic) ----------------
__global__ __launch_bounds__(256) void k_finalize(const uint16_t* __restrict__ fn,
                                                  const float* __restrict__ E_part,
                                                  float* __restrict__ out) {
    __shared__ float sm[4];
    int wid  = (blockIdx.x * blockDim.x + threadIdx.x) >> 6;   // one wave per row
    int lane = threadIdx.x & 63;
    int partner = (wid + HALF_N) & (N_ROWS - 1);
    const uint32_t* fr = (const uint32_t*)(fn + (size_t)wid * DIM);
    const uint32_t* pr = (const uint32_t*)(fn + (size_t)partner * DIM);
    uint32_t a = fr[lane], p = pr[lane];
    float a0 = bf_lo(a), a1 = bf_hi(a);
    float p0 = bf_lo(p), p1 = bf_hi(p);
    float sd = a0 * a0 + a1 * a1;       // self dot  (diagonal recompute)
    float pd = a0 * p0 + a1 * p1;       // positive-pair dot
    #pragma unroll
    for (int m = 1; m < 64; m <<= 1) {
        sd += __shfl_xor(sd, m, 64);
        pd += __shfl_xor(pd, m, 64);
    }
    float e = (lane < N_SLICES) ? E_part[(size_t)wid * N_SLICES + lane] : 0.0f;
    #pragma unroll
    for (int m = 1; m < 64; m <<= 1) e += __shfl_xor(e, m, 64);
    if (lane == 0) {
        float ep = e - fast_exp2(fmaf(sd, SCALE, -SCALE));   // remove diagonal
        sm[threadIdx.x >> 6] = INV_T + logf(ep) - pd * INV_T;
    }
    __syncthreads();
    if (threadIdx.x == 0)
        atomicAdd(out, (sm[0] + sm[1] + sm[2] + sm[3]) * (1.0f / N_ROWS));
}

extern "C" void kernel_launch(void* const* d_in, const int* in_sizes, int n_in,
                              void* d_out, int out_size, void* d_ws, size_t ws_size,
                              hipStream_t stream) {
    const float* feat = (const float*)d_in[0];
    float* out = (float*)d_out;

    // ws: fn (bf16, 2 MiB) | E_part (f32, 8192*32*4 = 1 MiB)
    uint16_t* fn  = (uint16_t*)d_ws;
    float* E_part = (float*)((char*)d_ws + (size_t)N_ROWS * DIM * 2);

    k_normalize<<<dim3(N_ROWS / 4), dim3(256), 0, stream>>>(feat, fn, out);
    k_simexp<<<dim3(N_ROWS / ROWS_PER_BLOCK, N_SLICES), dim3(256), 0, stream>>>(fn, E_part);
    k_finalize<<<dim3(N_ROWS / 4), dim3(256), 0, stream>>>(fn, E_part, out);
}